// Round 2
// baseline (376.050 us; speedup 1.0000x reference)
//
#include <hip/hip_runtime.h>

#define D_F 128
#define D_H 512
#define SHS 520     // sH row stride (bf16 elems): 1040 B, 16B-aligned
#define NGRID 512   // persistent grid: 2 blocks/CU x 256 CU, guaranteed co-resident

typedef short v8s __attribute__((ext_vector_type(8)));
typedef float v4f __attribute__((ext_vector_type(4)));
typedef _Float16 v2h __attribute__((ext_vector_type(2)));

__device__ inline unsigned short f2bf(float f) {
    unsigned u = __float_as_uint(f);
    unsigned r = (u + 0x7fffu + ((u >> 16) & 1u)) >> 16;   // RNE
    return (unsigned short)r;
}
__device__ inline v2h bch(unsigned x) { return __builtin_bit_cast(v2h, x); }

// ---------------------------------------------------------------------------
// prep: weight conversion (all blocks) + init cumsums/zeros/counters (block 0)
// ---------------------------------------------------------------------------
__global__ __launch_bounds__(256) void prep_kernel(
    const float* __restrict__ W1, const float* __restrict__ W2,
    const int* __restrict__ n_node, const int* __restrict__ n_edge,
    unsigned short* __restrict__ W1T, unsigned short* __restrict__ W2T,
    int* __restrict__ ec, int* __restrict__ nid,
    float* __restrict__ ew, float* __restrict__ ga,
    int* __restrict__ bar, int G, int E)
{
    if (blockIdx.x == 0) {
        __shared__ int sne[512];
        __shared__ int snn[512];
        const int t = threadIdx.x;
        if (t < 2) bar[t] = 0;                    // grid barrier + done counter
        for (int g = t; g < G; g += 256) { sne[g] = n_edge[g]; snn[g] = n_node[g]; }
        __syncthreads();
        for (int g = t; g < G; g += 256) {
            int se = 0, sn = 0;
            for (int k = 0; k < g; ++k)  se += sne[k];
            for (int k = 0; k <= g; ++k) sn += snn[k];
            ec[g]  = se;
            nid[g] = sn - 1;
            ew[g] = 0.f;
            ga[g] = 0.f;
            if (g == G - 1) {
                int tot = se + sne[g];
                ec[G] = tot > E ? tot : E;
            }
        }
    }
    int i = blockIdx.x * 256 + threadIdx.x;
    if (i < D_F * D_H) {
        int n = i >> 7, k = i & (D_F - 1);        // W1T[n][k] = W1[k][n]
        W1T[i] = f2bf(W1[k * D_H + n]);
        int n2 = i >> 9, k2 = i & (D_H - 1);      // W2T[n2][k2] = W2[k2][n2]
        W2T[i] = f2bf(W2[k2 * D_F + n2]);
    }
}

// ---------------------------------------------------------------------------
// Mega kernel: MLP phase -> grid spin-barrier -> edge phase -> last-block
// finalize. Persistent co-resident grid (see NGRID note). Collapses three
// kernel launches (and their AQL-barrier + L2 flush/inv boundaries) into one.
// ---------------------------------------------------------------------------
__global__ __launch_bounds__(512, 4) void mega_kernel(
    const float* __restrict__ nodes,
    const unsigned short* __restrict__ W1T, const float* __restrict__ b1,
    const unsigned short* __restrict__ W2T, const float* __restrict__ b2,
    _Float16* __restrict__ hh,
    const float* __restrict__ wedge,
    const int* __restrict__ senders, const int* __restrict__ receivers,
    const int* __restrict__ ec, const int* __restrict__ nid,
    float* __restrict__ ew, float* __restrict__ ga,
    int* __restrict__ bar, float* __restrict__ out,
    int N, int E, int G, int nblk, int ntiles)
{
    __shared__ __align__(16) char smem[32 * SHS * 2];   // 33280 B, aliased per phase
    unsigned short* sH = (unsigned short*)smem;

    const int t    = threadIdx.x;
    const int wave = t >> 6;        // 0..7
    const int lane = t & 63;
    const int li   = lane & 15;
    const int quad = lane >> 4;

    // ======================= Phase A: fused MLP =======================
    for (int tile = blockIdx.x; tile < nblk; tile += NGRID) {
        const int row0 = tile * 32;

        // A fragments: two 16-row groups (same for all 8 waves; L1-served)
        v8s a1[2][4];
        #pragma unroll
        for (int rg = 0; rg < 2; ++rg) {
            int r = min(row0 + rg * 16 + li, N - 1);
            const float* xp = nodes + (size_t)r * D_F + quad * 8;
            #pragma unroll
            for (int ks = 0; ks < 4; ++ks) {
                float4 f0 = *(const float4*)(xp + ks * 32);
                float4 f1 = *(const float4*)(xp + ks * 32 + 4);
                v8s v;
                v[0] = (short)f2bf(f0.x); v[1] = (short)f2bf(f0.y);
                v[2] = (short)f2bf(f0.z); v[3] = (short)f2bf(f0.w);
                v[4] = (short)f2bf(f1.x); v[5] = (short)f2bf(f1.y);
                v[6] = (short)f2bf(f1.z); v[7] = (short)f2bf(f1.w);
                a1[rg][ks] = v;
            }
        }

        // GEMM1: wave covers hidden cols [wave*64, wave*64+64)
        #pragma unroll 2
        for (int jj = 0; jj < 4; ++jj) {
            const int n0 = (wave * 4 + jj) * 16;
            const unsigned short* wp = W1T + (size_t)(n0 + li) * D_F + quad * 8;
            v4f acc0 = {0.f, 0.f, 0.f, 0.f};
            v4f acc1 = {0.f, 0.f, 0.f, 0.f};
            #pragma unroll
            for (int ks = 0; ks < 4; ++ks) {
                v8s b = *(const v8s*)(wp + ks * 32);
                acc0 = __builtin_amdgcn_mfma_f32_16x16x32_bf16(a1[0][ks], b, acc0, 0, 0, 0);
                acc1 = __builtin_amdgcn_mfma_f32_16x16x32_bf16(a1[1][ks], b, acc1, 0, 0, 0);
            }
            float bias = b1[n0 + li];
            #pragma unroll
            for (int r = 0; r < 4; ++r) {
                int m = quad * 4 + r;                 // C layout: row = quad*4+reg
                sH[m * SHS + n0 + li]        = f2bf(fmaxf(acc0[r] + bias, 0.f));
                sH[(16 + m) * SHS + n0 + li] = f2bf(fmaxf(acc1[r] + bias, 0.f));
            }
        }
        __syncthreads();

        // GEMM2: wave covers output cols [wave*16, wave*16+16); chunk-2 buffers
        {
            const int n0 = wave * 16;
            const unsigned short* wp = W2T + (size_t)(n0 + li) * D_H + quad * 8;
            v4f acc0 = {0.f, 0.f, 0.f, 0.f};
            v4f acc1 = {0.f, 0.f, 0.f, 0.f};
            #pragma unroll
            for (int kc = 0; kc < 8; ++kc) {
                v8s bb[2], aH0[2], aH1[2];
                #pragma unroll
                for (int u = 0; u < 2; ++u) {
                    int ks = kc * 2 + u;
                    bb[u]  = *(const v8s*)(wp + ks * 32);
                    aH0[u] = *(const v8s*)(sH + li * SHS + ks * 32 + quad * 8);
                    aH1[u] = *(const v8s*)(sH + (16 + li) * SHS + ks * 32 + quad * 8);
                }
                #pragma unroll
                for (int u = 0; u < 2; ++u) {
                    acc0 = __builtin_amdgcn_mfma_f32_16x16x32_bf16(aH0[u], bb[u], acc0, 0, 0, 0);
                    acc1 = __builtin_amdgcn_mfma_f32_16x16x32_bf16(aH1[u], bb[u], acc1, 0, 0, 0);
                }
            }
            float bias = b2[n0 + li];
            #pragma unroll
            for (int r = 0; r < 4; ++r) {
                int g0 = row0 + quad * 4 + r;
                if (g0 < N) hh[(size_t)g0 * D_F + n0 + li] = (_Float16)(acc0[r] + bias);
                int g1 = row0 + 16 + quad * 4 + r;
                if (g1 < N) hh[(size_t)g1 * D_F + n0 + li] = (_Float16)(acc1[r] + bias);
            }
        }
        __syncthreads();    // sH reuse safety for next grid-stride tile
    }

    // ================= grid barrier (all 512 blocks co-resident) =================
    __threadfence();                              // release: hh visible device-wide
    __syncthreads();
    if (t == 0) {
        atomicAdd(&bar[0], 1);
        while (atomicAdd(&bar[0], 0) < (int)gridDim.x) __builtin_amdgcn_s_sleep(2);
    }
    __syncthreads();
    __threadfence();                              // acquire: invalidate stale L1/L2

    // ======================= Phase B: edges =======================
    int*   sec = (int*)smem;                      // 513 ints
    float* sga = (float*)(smem + 2112);           // 512 floats (16B-aligned)
    float* sew = sga + 512;                       // 512 floats
    for (int i = t; i <= G; i += 512) sec[i] = ec[i];
    for (int i = t; i < G;  i += 512) { sga[i] = 0.f; sew[i] = 0.f; }
    __syncthreads();

    const unsigned* __restrict__ h32 = (const unsigned*)hh;   // row = 64 dwords
    const uint4*    __restrict__ h16 = (const uint4*)hh;      // row = 16 uint4

    for (int tile = blockIdx.x * 8 + wave; tile < ntiles; tile += NGRID * 8) {
        const int tbu = __builtin_amdgcn_readfirstlane(tile << 6);
        const int nt  = min(64, E - tbu);

        int gid;
        { int lo = 0, hi = G - 1;
          while (lo < hi) { int m = (lo + hi + 1) >> 1; if (sec[m] <= tbu) lo = m; else hi = m - 1; }
          gid = lo; }

        const int*   __restrict__ sp = senders   + tbu;
        const int*   __restrict__ rp = receivers + tbu;
        const float* __restrict__ wp = wedge     + tbu;

        if (nt == 64 && tbu + 64 <= sec[gid + 1]) {
            // fast path: full tile in one segment; 4 edges per dwordx4 load pair
            const bool q0 = (lane & 16) != 0;
            const bool q1 = (lane & 32) != 0;
            const int  c  = lane & 15;
            float accE = 0.f, accW = 0.f;         // accW counts each edge 16x
            #pragma unroll 1
            for (int i = 0; i < 64; i += 32) {
                uint4 a[8], b[8];
                #pragma unroll
                for (int u = 0; u < 8; ++u) {
                    int e = i + u * 4;
                    int s0 = sp[e], s1 = sp[e + 1], s2 = sp[e + 2], s3 = sp[e + 3];
                    int r0 = rp[e], r1 = rp[e + 1], r2 = rp[e + 2], r3 = rp[e + 3];
                    int sA = q0 ? s1 : s0;
                    int sB = q0 ? s3 : s2;
                    int s  = q1 ? sB : sA;
                    int rA = q0 ? r1 : r0;
                    int rB = q0 ? r3 : r2;
                    int r  = q1 ? rB : rA;
                    a[u] = h16[(unsigned)((s << 4) | c)];   // 4 rows / instr
                    b[u] = h16[(unsigned)((r << 4) | c)];
                }
                #pragma unroll
                for (int u = 0; u < 8; ++u) {
                    int e = i + u * 4;
                    float w0 = wp[e], w1 = wp[e + 1], w2 = wp[e + 2], w3 = wp[e + 3];
                    float wA = q0 ? w1 : w0;
                    float wB = q0 ? w3 : w2;
                    float w  = q1 ? wB : wA;
                    v2h d0 = bch(a[u].x) - bch(b[u].x);
                    v2h d1 = bch(a[u].y) - bch(b[u].y);
                    v2h d2 = bch(a[u].z) - bch(b[u].z);
                    v2h d3 = bch(a[u].w) - bch(b[u].w);
                    float tt = __builtin_amdgcn_fdot2(d0, d0, 0.f, false);
                    tt = __builtin_amdgcn_fdot2(d1, d1, tt, false);
                    tt = __builtin_amdgcn_fdot2(d2, d2, tt, false);
                    tt = __builtin_amdgcn_fdot2(d3, d3, tt, false);
                    accE = fmaf(w, tt, accE);
                    accW += w;
                }
            }
            float rE = accE, rW = accW;
            #pragma unroll
            for (int m = 32; m > 0; m >>= 1) {
                rE += __shfl_xor(rE, m);
                rW += __shfl_xor(rW, m);
            }
            if (lane == 0) {
                atomicAdd(&sga[gid], rE);
                atomicAdd(&sew[gid], rW * 0.0625f);   // / 16 lanes per edge
            }
        } else {
            // slow path: per-edge with segment flushes (uniform loads)
            float accE = 0.f, accW = 0.f;
            for (int i = 0; i < nt; ++i) {
                int e = tbu + i;
                while (e >= sec[gid + 1]) {
                    float rE = accE;
                    #pragma unroll
                    for (int m = 32; m > 0; m >>= 1) rE += __shfl_xor(rE, m);
                    if (lane == 0 && (rE != 0.f || accW != 0.f)) {
                        atomicAdd(&sga[gid], rE);
                        atomicAdd(&sew[gid], accW);
                    }
                    accE = 0.f; accW = 0.f;
                    ++gid;
                }
                int   s = sp[i];
                int   r = rp[i];
                float w = wp[i];
                unsigned a = h32[(unsigned)((s << 6) | lane)];
                unsigned b = h32[(unsigned)((r << 6) | lane)];
                v2h d = bch(a) - bch(b);
                float tt = __builtin_amdgcn_fdot2(d, d, 0.f, false);
                accE = fmaf(w, tt, accE);
                accW += w;
            }
            float rE = accE;
            #pragma unroll
            for (int m = 32; m > 0; m >>= 1) rE += __shfl_xor(rE, m);
            if (lane == 0 && (rE != 0.f || accW != 0.f)) {
                atomicAdd(&sga[gid], rE);
                atomicAdd(&sew[gid], accW);
            }
        }
    }

    __syncthreads();
    for (int g = t; g < G; g += 512) {
        float vg = sga[g], vw = sew[g];
        if (vg != 0.f || vw != 0.f) {
            atomicAdd(&ga[g], vg);
            atomicAdd(&ew[g], vw);
        }
    }

    // ================= last-block finalize =================
    __threadfence();                 // order ga/ew atomics before done-counter
    __syncthreads();
    if (t == 0) {
        int old = atomicAdd(&bar[1], 1);
        sec[0] = (old == (int)gridDim.x - 1) ? 1 : 0;
    }
    __syncthreads();
    if (sec[0]) {
        // node_out gather: out[g][c] = (float)hh[nid[g]][c]
        for (int i = t; i < G * D_F; i += 512) {
            int g = i >> 7, c = i & (D_F - 1);
            out[i] = (float)hh[(size_t)nid[g] * D_F + c];
        }
        // loss = mean_g (ew!=0 ? ga/ew : 0); coherent reads via atomic fetch-add 0
        float p = 0.f;
        for (int g = t; g < G; g += 512) {
            float w = atomicAdd(&ew[g], 0.f);
            float v = atomicAdd(&ga[g], 0.f);
            p += (w != 0.f) ? v / w : 0.f;
        }
        #pragma unroll
        for (int m = 32; m > 0; m >>= 1) p += __shfl_xor(p, m);
        if (lane == 0) sga[wave] = p;
        __syncthreads();
        if (t == 0) {
            float s = 0.f;
            #pragma unroll
            for (int w = 0; w < 8; ++w) s += sga[w];
            out[(size_t)G * D_F] = s / (float)G;
        }
    }
}

// ---------------------------------------------------------------------------
extern "C" void kernel_launch(void* const* d_in, const int* in_sizes, int n_in,
                              void* d_out, int out_size, void* d_ws, size_t ws_size,
                              hipStream_t stream) {
    const float* nodes     = (const float*)d_in[0];
    const float* edges     = (const float*)d_in[1];
    const int*   senders   = (const int*)d_in[2];
    const int*   receivers = (const int*)d_in[3];
    const int*   n_node    = (const int*)d_in[4];
    const int*   n_edge    = (const int*)d_in[5];
    const float* W1        = (const float*)d_in[6];
    const float* b1        = (const float*)d_in[7];
    const float* W2        = (const float*)d_in[8];
    const float* b2        = (const float*)d_in[9];

    const int N = in_sizes[0] / D_F;
    const int E = in_sizes[1];
    const int G = in_sizes[4];

    float* out = (float*)d_out;

    // workspace: hh f16 | W1T bf16 | W2T bf16 | ec | nid | ew | ga | bar
    _Float16*       hh  = (_Float16*)d_ws;
    unsigned short* W1T = (unsigned short*)(hh + (size_t)N * D_F);
    unsigned short* W2T = W1T + (size_t)D_F * D_H;
    int*            ec  = (int*)(W2T + (size_t)D_F * D_H);
    int*            nid = ec + (G + 1);
    float*          ew  = (float*)(nid + G);
    float*          ga  = ew + G;
    int*            bar = (int*)(ga + G);

    prep_kernel<<<(D_F * D_H + 255) / 256, 256, 0, stream>>>(
        W1, W2, n_node, n_edge, W1T, W2T, ec, nid, ew, ga, bar, G, E);

    const int nblk   = (N + 31) / 32;          // 32-row MLP tiles
    const int ntiles = (E + 63) / 64;          // 64-edge tiles

    mega_kernel<<<NGRID, 512, 0, stream>>>(
        nodes, W1T, b1, W2T, b2, hh, edges, senders, receivers,
        ec, nid, ew, ga, bar, out, N, E, G, nblk, ntiles);
}

// Round 3
// 234.239 us; speedup vs baseline: 1.6054x; 1.6054x over previous
//
#include <hip/hip_runtime.h>

#define D_F 128
#define D_H 512
#define SHS 520     // sH row stride (bf16 elems): 1040 B, 16B-aligned
#define NGRID 512   // persistent grid: 2 blocks/CU x 256 CU, guaranteed co-resident
                    // (launch_bounds(512,4) caps VGPR<=128 -> >=16 waves/CU; LDS 33280B -> >=2 blk/CU)

typedef short v8s __attribute__((ext_vector_type(8)));
typedef float v4f __attribute__((ext_vector_type(4)));
typedef _Float16 v2h __attribute__((ext_vector_type(2)));

__device__ inline unsigned short f2bf(float f) {
    unsigned u = __float_as_uint(f);
    unsigned r = (u + 0x7fffu + ((u >> 16) & 1u)) >> 16;   // RNE
    return (unsigned short)r;
}
__device__ inline v2h bch(unsigned x) { return __builtin_bit_cast(v2h, x); }

// ---------------------------------------------------------------------------
// prep: weight conversion (all blocks) + init cumsums/zeros/counters (block 0)
// ---------------------------------------------------------------------------
__global__ __launch_bounds__(256) void prep_kernel(
    const float* __restrict__ W1, const float* __restrict__ W2,
    const int* __restrict__ n_node, const int* __restrict__ n_edge,
    unsigned short* __restrict__ W1T, unsigned short* __restrict__ W2T,
    int* __restrict__ ec, int* __restrict__ nid,
    float* __restrict__ ew, float* __restrict__ ga,
    int* __restrict__ bar, int G, int E)
{
    if (blockIdx.x == 0) {
        __shared__ int sne[512];
        __shared__ int snn[512];
        const int t = threadIdx.x;
        if (t < 2) bar[t] = 0;                    // grid barrier + done counter
        for (int g = t; g < G; g += 256) { sne[g] = n_edge[g]; snn[g] = n_node[g]; }
        __syncthreads();
        for (int g = t; g < G; g += 256) {
            int se = 0, sn = 0;
            for (int k = 0; k < g; ++k)  se += sne[k];
            for (int k = 0; k <= g; ++k) sn += snn[k];
            ec[g]  = se;
            nid[g] = sn - 1;
            ew[g] = 0.f;
            ga[g] = 0.f;
            if (g == G - 1) {
                int tot = se + sne[g];
                ec[G] = tot > E ? tot : E;
            }
        }
    }
    int i = blockIdx.x * 256 + threadIdx.x;
    if (i < D_F * D_H) {
        int n = i >> 7, k = i & (D_F - 1);        // W1T[n][k] = W1[k][n]
        W1T[i] = f2bf(W1[k * D_H + n]);
        int n2 = i >> 9, k2 = i & (D_H - 1);      // W2T[n2][k2] = W2[k2][n2]
        W2T[i] = f2bf(W2[k2 * D_F + n2]);
    }
}

// ---------------------------------------------------------------------------
// Mega kernel: MLP phase -> grid barrier (LOAD-poll, not RMW-poll: round-2's
// atomicAdd(p,0) polling serialized 512 blocks at the coherence point and
// cost ~250 us) -> edge phase -> last-block finalize.
// ---------------------------------------------------------------------------
__global__ __launch_bounds__(512, 4) void mega_kernel(
    const float* __restrict__ nodes,
    const unsigned short* __restrict__ W1T, const float* __restrict__ b1,
    const unsigned short* __restrict__ W2T, const float* __restrict__ b2,
    _Float16* __restrict__ hh,
    const float* __restrict__ wedge,
    const int* __restrict__ senders, const int* __restrict__ receivers,
    const int* __restrict__ ec, const int* __restrict__ nid,
    float* __restrict__ ew, float* __restrict__ ga,
    int* __restrict__ bar, float* __restrict__ out,
    int N, int E, int G, int nblk, int ntiles)
{
    __shared__ __align__(16) char smem[32 * SHS * 2];   // 33280 B, aliased per phase
    unsigned short* sH = (unsigned short*)smem;

    const int t    = threadIdx.x;
    const int wave = t >> 6;        // 0..7
    const int lane = t & 63;
    const int li   = lane & 15;
    const int quad = lane >> 4;

    // ======================= Phase A: fused MLP =======================
    for (int tile = blockIdx.x; tile < nblk; tile += NGRID) {
        const int row0 = tile * 32;

        // A fragments: two 16-row groups (same for all 8 waves; L1-served)
        v8s a1[2][4];
        #pragma unroll
        for (int rg = 0; rg < 2; ++rg) {
            int r = min(row0 + rg * 16 + li, N - 1);
            const float* xp = nodes + (size_t)r * D_F + quad * 8;
            #pragma unroll
            for (int ks = 0; ks < 4; ++ks) {
                float4 f0 = *(const float4*)(xp + ks * 32);
                float4 f1 = *(const float4*)(xp + ks * 32 + 4);
                v8s v;
                v[0] = (short)f2bf(f0.x); v[1] = (short)f2bf(f0.y);
                v[2] = (short)f2bf(f0.z); v[3] = (short)f2bf(f0.w);
                v[4] = (short)f2bf(f1.x); v[5] = (short)f2bf(f1.y);
                v[6] = (short)f2bf(f1.z); v[7] = (short)f2bf(f1.w);
                a1[rg][ks] = v;
            }
        }

        // GEMM1: wave covers hidden cols [wave*64, wave*64+64)
        #pragma unroll 2
        for (int jj = 0; jj < 4; ++jj) {
            const int n0 = (wave * 4 + jj) * 16;
            const unsigned short* wp = W1T + (size_t)(n0 + li) * D_F + quad * 8;
            v4f acc0 = {0.f, 0.f, 0.f, 0.f};
            v4f acc1 = {0.f, 0.f, 0.f, 0.f};
            #pragma unroll
            for (int ks = 0; ks < 4; ++ks) {
                v8s b = *(const v8s*)(wp + ks * 32);
                acc0 = __builtin_amdgcn_mfma_f32_16x16x32_bf16(a1[0][ks], b, acc0, 0, 0, 0);
                acc1 = __builtin_amdgcn_mfma_f32_16x16x32_bf16(a1[1][ks], b, acc1, 0, 0, 0);
            }
            float bias = b1[n0 + li];
            #pragma unroll
            for (int r = 0; r < 4; ++r) {
                int m = quad * 4 + r;                 // C layout: row = quad*4+reg
                sH[m * SHS + n0 + li]        = f2bf(fmaxf(acc0[r] + bias, 0.f));
                sH[(16 + m) * SHS + n0 + li] = f2bf(fmaxf(acc1[r] + bias, 0.f));
            }
        }
        __syncthreads();

        // GEMM2: wave covers output cols [wave*16, wave*16+16); chunk-2 buffers
        {
            const int n0 = wave * 16;
            const unsigned short* wp = W2T + (size_t)(n0 + li) * D_H + quad * 8;
            v4f acc0 = {0.f, 0.f, 0.f, 0.f};
            v4f acc1 = {0.f, 0.f, 0.f, 0.f};
            #pragma unroll
            for (int kc = 0; kc < 8; ++kc) {
                v8s bb[2], aH0[2], aH1[2];
                #pragma unroll
                for (int u = 0; u < 2; ++u) {
                    int ks = kc * 2 + u;
                    bb[u]  = *(const v8s*)(wp + ks * 32);
                    aH0[u] = *(const v8s*)(sH + li * SHS + ks * 32 + quad * 8);
                    aH1[u] = *(const v8s*)(sH + (16 + li) * SHS + ks * 32 + quad * 8);
                }
                #pragma unroll
                for (int u = 0; u < 2; ++u) {
                    acc0 = __builtin_amdgcn_mfma_f32_16x16x32_bf16(aH0[u], bb[u], acc0, 0, 0, 0);
                    acc1 = __builtin_amdgcn_mfma_f32_16x16x32_bf16(aH1[u], bb[u], acc1, 0, 0, 0);
                }
            }
            float bias = b2[n0 + li];
            #pragma unroll
            for (int r = 0; r < 4; ++r) {
                int g0 = row0 + quad * 4 + r;
                if (g0 < N) hh[(size_t)g0 * D_F + n0 + li] = (_Float16)(acc0[r] + bias);
                int g1 = row0 + 16 + quad * 4 + r;
                if (g1 < N) hh[(size_t)g1 * D_F + n0 + li] = (_Float16)(acc1[r] + bias);
            }
        }
        __syncthreads();    // sH reuse safety for next grid-stride tile
    }

    // ===== grid barrier: release-RMW arrive, acquire-LOAD poll (no RMW spin) =====
    __syncthreads();                 // drains this block's hh stores (vmcnt 0)
    if (t == 0) {
        __hip_atomic_fetch_add(&bar[0], 1, __ATOMIC_RELEASE, __HIP_MEMORY_SCOPE_AGENT);
        while (__hip_atomic_load(&bar[0], __ATOMIC_ACQUIRE, __HIP_MEMORY_SCOPE_AGENT)
               < NGRID)
            __builtin_amdgcn_s_sleep(8);
    }
    __syncthreads();

    // ======================= Phase B: edges =======================
    int*   sec = (int*)smem;                      // 513 ints
    float* sga = (float*)(smem + 2112);           // 512 floats (16B-aligned)
    float* sew = sga + 512;                       // 512 floats
    for (int i = t; i <= G; i += 512) sec[i] = ec[i];
    for (int i = t; i < G;  i += 512) { sga[i] = 0.f; sew[i] = 0.f; }
    __syncthreads();

    const unsigned* __restrict__ h32 = (const unsigned*)hh;   // row = 64 dwords
    const uint4*    __restrict__ h16 = (const uint4*)hh;      // row = 16 uint4

    for (int tile = blockIdx.x * 8 + wave; tile < ntiles; tile += NGRID * 8) {
        const int tbu = __builtin_amdgcn_readfirstlane(tile << 6);
        const int nt  = min(64, E - tbu);

        int gid;
        { int lo = 0, hi = G - 1;
          while (lo < hi) { int m = (lo + hi + 1) >> 1; if (sec[m] <= tbu) lo = m; else hi = m - 1; }
          gid = lo; }

        const int*   __restrict__ sp = senders   + tbu;
        const int*   __restrict__ rp = receivers + tbu;
        const float* __restrict__ wp = wedge     + tbu;

        if (nt == 64 && tbu + 64 <= sec[gid + 1]) {
            // fast path: full tile in one segment; 4 edges per dwordx4 load pair
            const bool q0 = (lane & 16) != 0;
            const bool q1 = (lane & 32) != 0;
            const int  c  = lane & 15;
            float accE = 0.f, accW = 0.f;         // accW counts each edge 16x
            #pragma unroll 1
            for (int i = 0; i < 64; i += 32) {
                uint4 a[8], b[8];
                #pragma unroll
                for (int u = 0; u < 8; ++u) {
                    int e = i + u * 4;
                    int s0 = sp[e], s1 = sp[e + 1], s2 = sp[e + 2], s3 = sp[e + 3];
                    int r0 = rp[e], r1 = rp[e + 1], r2 = rp[e + 2], r3 = rp[e + 3];
                    int sA = q0 ? s1 : s0;
                    int sB = q0 ? s3 : s2;
                    int s  = q1 ? sB : sA;
                    int rA = q0 ? r1 : r0;
                    int rB = q0 ? r3 : r2;
                    int r  = q1 ? rB : rA;
                    a[u] = h16[(unsigned)((s << 4) | c)];   // 4 rows / instr
                    b[u] = h16[(unsigned)((r << 4) | c)];
                }
                #pragma unroll
                for (int u = 0; u < 8; ++u) {
                    int e = i + u * 4;
                    float w0 = wp[e], w1 = wp[e + 1], w2 = wp[e + 2], w3 = wp[e + 3];
                    float wA = q0 ? w1 : w0;
                    float wB = q0 ? w3 : w2;
                    float w  = q1 ? wB : wA;
                    v2h d0 = bch(a[u].x) - bch(b[u].x);
                    v2h d1 = bch(a[u].y) - bch(b[u].y);
                    v2h d2 = bch(a[u].z) - bch(b[u].z);
                    v2h d3 = bch(a[u].w) - bch(b[u].w);
                    float tt = __builtin_amdgcn_fdot2(d0, d0, 0.f, false);
                    tt = __builtin_amdgcn_fdot2(d1, d1, tt, false);
                    tt = __builtin_amdgcn_fdot2(d2, d2, tt, false);
                    tt = __builtin_amdgcn_fdot2(d3, d3, tt, false);
                    accE = fmaf(w, tt, accE);
                    accW += w;
                }
            }
            float rE = accE, rW = accW;
            #pragma unroll
            for (int m = 32; m > 0; m >>= 1) {
                rE += __shfl_xor(rE, m);
                rW += __shfl_xor(rW, m);
            }
            if (lane == 0) {
                atomicAdd(&sga[gid], rE);
                atomicAdd(&sew[gid], rW * 0.0625f);   // / 16 lanes per edge
            }
        } else {
            // slow path: per-edge with segment flushes (uniform loads)
            float accE = 0.f, accW = 0.f;
            for (int i = 0; i < nt; ++i) {
                int e = tbu + i;
                while (e >= sec[gid + 1]) {
                    float rE = accE;
                    #pragma unroll
                    for (int m = 32; m > 0; m >>= 1) rE += __shfl_xor(rE, m);
                    if (lane == 0 && (rE != 0.f || accW != 0.f)) {
                        atomicAdd(&sga[gid], rE);
                        atomicAdd(&sew[gid], accW);
                    }
                    accE = 0.f; accW = 0.f;
                    ++gid;
                }
                int   s = sp[i];
                int   r = rp[i];
                float w = wp[i];
                unsigned a = h32[(unsigned)((s << 6) | lane)];
                unsigned b = h32[(unsigned)((r << 6) | lane)];
                v2h d = bch(a) - bch(b);
                float tt = __builtin_amdgcn_fdot2(d, d, 0.f, false);
                accE = fmaf(w, tt, accE);
                accW += w;
            }
            float rE = accE;
            #pragma unroll
            for (int m = 32; m > 0; m >>= 1) rE += __shfl_xor(rE, m);
            if (lane == 0 && (rE != 0.f || accW != 0.f)) {
                atomicAdd(&sga[gid], rE);
                atomicAdd(&sew[gid], accW);
            }
        }
    }

    __syncthreads();
    for (int g = t; g < G; g += 512) {
        float vg = sga[g], vw = sew[g];
        if (vg != 0.f || vw != 0.f) {
            atomicAdd(&ga[g], vg);
            atomicAdd(&ew[g], vw);
        }
    }

    // ================= last-block finalize =================
    __syncthreads();                 // drains this block's ga/ew atomics
    if (t == 0) {
        int old = __hip_atomic_fetch_add(&bar[1], 1, __ATOMIC_ACQ_REL,
                                         __HIP_MEMORY_SCOPE_AGENT);
        sec[0] = (old == NGRID - 1) ? 1 : 0;
    }
    __syncthreads();
    if (sec[0]) {
        // node_out gather: out[g][c] = (float)hh[nid[g]][c]
        for (int i = t; i < G * D_F; i += 512) {
            int g = i >> 7, c = i & (D_F - 1);
            out[i] = (float)hh[(size_t)nid[g] * D_F + c];
        }
        // loss = mean_g (ew!=0 ? ga/ew : 0); coherent reads via atomic loads
        float p = 0.f;
        for (int g = t; g < G; g += 512) {
            float w = __hip_atomic_load(&ew[g], __ATOMIC_RELAXED, __HIP_MEMORY_SCOPE_AGENT);
            float v = __hip_atomic_load(&ga[g], __ATOMIC_RELAXED, __HIP_MEMORY_SCOPE_AGENT);
            p += (w != 0.f) ? v / w : 0.f;
        }
        #pragma unroll
        for (int m = 32; m > 0; m >>= 1) p += __shfl_xor(p, m);
        if (lane == 0) sga[wave] = p;
        __syncthreads();
        if (t == 0) {
            float s = 0.f;
            #pragma unroll
            for (int w = 0; w < 8; ++w) s += sga[w];
            out[(size_t)G * D_F] = s / (float)G;
        }
    }
}

// ---------------------------------------------------------------------------
extern "C" void kernel_launch(void* const* d_in, const int* in_sizes, int n_in,
                              void* d_out, int out_size, void* d_ws, size_t ws_size,
                              hipStream_t stream) {
    const float* nodes     = (const float*)d_in[0];
    const float* edges     = (const float*)d_in[1];
    const int*   senders   = (const int*)d_in[2];
    const int*   receivers = (const int*)d_in[3];
    const int*   n_node    = (const int*)d_in[4];
    const int*   n_edge    = (const int*)d_in[5];
    const float* W1        = (const float*)d_in[6];
    const float* b1        = (const float*)d_in[7];
    const float* W2        = (const float*)d_in[8];
    const float* b2        = (const float*)d_in[9];

    const int N = in_sizes[0] / D_F;
    const int E = in_sizes[1];
    const int G = in_sizes[4];

    float* out = (float*)d_out;

    // workspace: hh f16 | W1T bf16 | W2T bf16 | ec | nid | ew | ga | bar
    _Float16*       hh  = (_Float16*)d_ws;
    unsigned short* W1T = (unsigned short*)(hh + (size_t)N * D_F);
    unsigned short* W2T = W1T + (size_t)D_F * D_H;
    int*            ec  = (int*)(W2T + (size_t)D_F * D_H);
    int*            nid = ec + (G + 1);
    float*          ew  = (float*)(nid + G);
    float*          ga  = ew + G;
    int*            bar = (int*)(ga + G);

    prep_kernel<<<(D_F * D_H + 255) / 256, 256, 0, stream>>>(
        W1, W2, n_node, n_edge, W1T, W2T, ec, nid, ew, ga, bar, G, E);

    const int nblk   = (N + 31) / 32;          // 32-row MLP tiles
    const int ntiles = (E + 63) / 64;          // 64-edge tiles

    mega_kernel<<<NGRID, 512, 0, stream>>>(
        nodes, W1T, b1, W2T, b2, hh, edges, senders, receivers,
        ec, nid, ew, ga, bar, out, N, E, G, nblk, ntiles);
}

// Round 4
// 154.607 us; speedup vs baseline: 2.4323x; 1.5151x over previous
//
#include <hip/hip_runtime.h>

#define D_F 128
#define D_H 512
#define SHS 520     // sH row stride (bf16 elems): 1040 B, 16B-aligned
#define SOS 136     // sOut row stride (f16 elems): 272 B, 16B-aligned, depadded banks
#define NGRID 512   // persistent grid: 2 blocks/CU x 256 CU, guaranteed co-resident
                    // (launch_bounds(512,4) caps VGPR<=128 -> >=16 waves/CU; LDS 33280B -> >=2 blk/CU)

typedef short v8s __attribute__((ext_vector_type(8)));
typedef float v4f __attribute__((ext_vector_type(4)));
typedef _Float16 v2h __attribute__((ext_vector_type(2)));

__device__ inline unsigned short f2bf(float f) {
    unsigned u = __float_as_uint(f);
    unsigned r = (u + 0x7fffu + ((u >> 16) & 1u)) >> 16;   // RNE
    return (unsigned short)r;
}
__device__ inline v2h bch(unsigned x) { return __builtin_bit_cast(v2h, x); }

// ---------------------------------------------------------------------------
// prep: weight conversion (all blocks) + init cumsums/zeros/counters (block 0)
// ---------------------------------------------------------------------------
__global__ __launch_bounds__(256) void prep_kernel(
    const float* __restrict__ W1, const float* __restrict__ W2,
    const int* __restrict__ n_node, const int* __restrict__ n_edge,
    unsigned short* __restrict__ W1T, unsigned short* __restrict__ W2T,
    int* __restrict__ ec, int* __restrict__ nid,
    float* __restrict__ ew, float* __restrict__ ga,
    int* __restrict__ bar, int G, int E)
{
    if (blockIdx.x == 0) {
        __shared__ int sne[512];
        __shared__ int snn[512];
        const int t = threadIdx.x;
        if (t < 2) bar[t] = 0;                    // grid barrier + done counter
        for (int g = t; g < G; g += 256) { sne[g] = n_edge[g]; snn[g] = n_node[g]; }
        __syncthreads();
        for (int g = t; g < G; g += 256) {
            int se = 0, sn = 0;
            for (int k = 0; k < g; ++k)  se += sne[k];
            for (int k = 0; k <= g; ++k) sn += snn[k];
            ec[g]  = se;
            nid[g] = sn - 1;
            ew[g] = 0.f;
            ga[g] = 0.f;
            if (g == G - 1) {
                int tot = se + sne[g];
                ec[G] = tot > E ? tot : E;
            }
        }
    }
    int i = blockIdx.x * 256 + threadIdx.x;
    if (i < D_F * D_H) {
        int n = i >> 7, k = i & (D_F - 1);        // W1T[n][k] = W1[k][n]
        W1T[i] = f2bf(W1[k * D_H + n]);
        int n2 = i >> 9, k2 = i & (D_H - 1);      // W2T[n2][k2] = W2[k2][n2]
        W2T[i] = f2bf(W2[k2 * D_F + n2]);
    }
}

// ---------------------------------------------------------------------------
// Mega kernel. Sync design (round-4): hh is written WRITE-THROUGH (system-
// scope relaxed stores, sc0 sc1 -> lands at IF$, never dirty in a per-XCD
// L2). Therefore the grid barrier needs NO buffer_wbl2 / buffer_inv:
//   release = __syncthreads (drains vmcnt; write-through => globally visible)
//             + RELAXED arrive RMW (agent, IF$-served)
//   poll    = RELAXED agent load + s_sleep (no per-iteration cache inv)
//   acquire = compiler barrier only (no L2 ever held a stale hh line; HW
//             cannot issue phase-B loads past the value-dependent spin branch)
// Round-3's RELEASE/ACQUIRE ops cost ~100us in wbl2/inv storms (512 blocks).
// ---------------------------------------------------------------------------
__global__ __launch_bounds__(512, 4) void mega_kernel(
    const float* __restrict__ nodes,
    const unsigned short* __restrict__ W1T, const float* __restrict__ b1,
    const unsigned short* __restrict__ W2T, const float* __restrict__ b2,
    _Float16* __restrict__ hh,
    const float* __restrict__ wedge,
    const int* __restrict__ senders, const int* __restrict__ receivers,
    const int* __restrict__ ec, const int* __restrict__ nid,
    float* __restrict__ ew, float* __restrict__ ga,
    int* __restrict__ bar, float* __restrict__ out,
    int N, int E, int G, int nblk, int ntiles)
{
    __shared__ __align__(16) char smem[32 * SHS * 2];   // 33280 B, aliased per phase
    unsigned short* sH = (unsigned short*)smem;

    const int t    = threadIdx.x;
    const int wave = t >> 6;        // 0..7
    const int lane = t & 63;
    const int li   = lane & 15;
    const int quad = lane >> 4;

    // ======================= Phase A: fused MLP =======================
    for (int tile = blockIdx.x; tile < nblk; tile += NGRID) {
        const int row0 = tile * 32;

        // A fragments: two 16-row groups (same for all 8 waves; L1-served)
        v8s a1[2][4];
        #pragma unroll
        for (int rg = 0; rg < 2; ++rg) {
            int r = min(row0 + rg * 16 + li, N - 1);
            const float* xp = nodes + (size_t)r * D_F + quad * 8;
            #pragma unroll
            for (int ks = 0; ks < 4; ++ks) {
                float4 f0 = *(const float4*)(xp + ks * 32);
                float4 f1 = *(const float4*)(xp + ks * 32 + 4);
                v8s v;
                v[0] = (short)f2bf(f0.x); v[1] = (short)f2bf(f0.y);
                v[2] = (short)f2bf(f0.z); v[3] = (short)f2bf(f0.w);
                v[4] = (short)f2bf(f1.x); v[5] = (short)f2bf(f1.y);
                v[6] = (short)f2bf(f1.z); v[7] = (short)f2bf(f1.w);
                a1[rg][ks] = v;
            }
        }

        // GEMM1: wave covers hidden cols [wave*64, wave*64+64)
        #pragma unroll 2
        for (int jj = 0; jj < 4; ++jj) {
            const int n0 = (wave * 4 + jj) * 16;
            const unsigned short* wp = W1T + (size_t)(n0 + li) * D_F + quad * 8;
            v4f acc0 = {0.f, 0.f, 0.f, 0.f};
            v4f acc1 = {0.f, 0.f, 0.f, 0.f};
            #pragma unroll
            for (int ks = 0; ks < 4; ++ks) {
                v8s b = *(const v8s*)(wp + ks * 32);
                acc0 = __builtin_amdgcn_mfma_f32_16x16x32_bf16(a1[0][ks], b, acc0, 0, 0, 0);
                acc1 = __builtin_amdgcn_mfma_f32_16x16x32_bf16(a1[1][ks], b, acc1, 0, 0, 0);
            }
            float bias = b1[n0 + li];
            #pragma unroll
            for (int r = 0; r < 4; ++r) {
                int m = quad * 4 + r;                 // C layout: row = quad*4+reg
                sH[m * SHS + n0 + li]        = f2bf(fmaxf(acc0[r] + bias, 0.f));
                sH[(16 + m) * SHS + n0 + li] = f2bf(fmaxf(acc1[r] + bias, 0.f));
            }
        }
        __syncthreads();

        // GEMM2: wave covers output cols [wave*16, wave*16+16); chunk-2 buffers
        {
            const int n0 = wave * 16;
            const unsigned short* wp = W2T + (size_t)(n0 + li) * D_H + quad * 8;
            v4f acc0 = {0.f, 0.f, 0.f, 0.f};
            v4f acc1 = {0.f, 0.f, 0.f, 0.f};
            #pragma unroll
            for (int kc = 0; kc < 8; ++kc) {
                v8s bb[2], aH0[2], aH1[2];
                #pragma unroll
                for (int u = 0; u < 2; ++u) {
                    int ks = kc * 2 + u;
                    bb[u]  = *(const v8s*)(wp + ks * 32);
                    aH0[u] = *(const v8s*)(sH + li * SHS + ks * 32 + quad * 8);
                    aH1[u] = *(const v8s*)(sH + (16 + li) * SHS + ks * 32 + quad * 8);
                }
                #pragma unroll
                for (int u = 0; u < 2; ++u) {
                    acc0 = __builtin_amdgcn_mfma_f32_16x16x32_bf16(aH0[u], bb[u], acc0, 0, 0, 0);
                    acc1 = __builtin_amdgcn_mfma_f32_16x16x32_bf16(aH1[u], bb[u], acc1, 0, 0, 0);
                }
            }
            float bias = b2[n0 + li];

            // epilogue: stage 32x128 f16 in LDS, then WRITE-THROUGH 16B/thread
            __syncthreads();                      // all waves done reading sH
            _Float16* sOut = (_Float16*)smem;     // 32 x SOS f16
            #pragma unroll
            for (int r = 0; r < 4; ++r) {
                sOut[(quad * 4 + r) * SOS + n0 + li]      = (_Float16)(acc0[r] + bias);
                sOut[(16 + quad * 4 + r) * SOS + n0 + li] = (_Float16)(acc1[r] + bias);
            }
            __syncthreads();
            {
                int row = t >> 4;                 // 0..31
                int seg = t & 15;                 // 16B segment within row
                int g = row0 + row;
                if (g < N) {
                    const _Float16* s = sOut + row * SOS + seg * 8;
                    unsigned long long v0 = *(const unsigned long long*)(s);
                    unsigned long long v1 = *(const unsigned long long*)(s + 4);
                    unsigned long long* gp = (unsigned long long*)(hh + (size_t)g * D_F + seg * 8);
                    __hip_atomic_store(gp,     v0, __ATOMIC_RELAXED, __HIP_MEMORY_SCOPE_SYSTEM);
                    __hip_atomic_store(gp + 1, v1, __ATOMIC_RELAXED, __HIP_MEMORY_SCOPE_SYSTEM);
                }
            }
        }
        __syncthreads();    // smem reuse safety for next grid-stride tile
    }

    // ==== grid barrier: relaxed arrive + relaxed poll (no wbl2, no inv) ====
    __syncthreads();                 // drains vmcnt: write-through hh stores visible
    if (t == 0) {
        atomicAdd(&bar[0], 1);       // agent relaxed RMW, IF$-served
        while (__hip_atomic_load(&bar[0], __ATOMIC_RELAXED, __HIP_MEMORY_SCOPE_AGENT)
               < NGRID)
            __builtin_amdgcn_s_sleep(16);
    }
    asm volatile("" ::: "memory");   // compiler: no hoisting of phase-B loads
    __syncthreads();

    // ======================= Phase B: edges =======================
    int*   sec = (int*)smem;                      // 513 ints
    float* sga = (float*)(smem + 2112);           // 512 floats (16B-aligned)
    float* sew = sga + 512;                       // 512 floats
    for (int i = t; i <= G; i += 512) sec[i] = ec[i];
    for (int i = t; i < G;  i += 512) { sga[i] = 0.f; sew[i] = 0.f; }
    __syncthreads();

    const unsigned* __restrict__ h32 = (const unsigned*)hh;   // row = 64 dwords
    const uint4*    __restrict__ h16 = (const uint4*)hh;      // row = 16 uint4

    for (int tile = blockIdx.x * 8 + wave; tile < ntiles; tile += NGRID * 8) {
        const int tbu = __builtin_amdgcn_readfirstlane(tile << 6);
        const int nt  = min(64, E - tbu);

        int gid;
        { int lo = 0, hi = G - 1;
          while (lo < hi) { int m = (lo + hi + 1) >> 1; if (sec[m] <= tbu) lo = m; else hi = m - 1; }
          gid = lo; }

        const int*   __restrict__ sp = senders   + tbu;
        const int*   __restrict__ rp = receivers + tbu;
        const float* __restrict__ wp = wedge     + tbu;

        if (nt == 64 && tbu + 64 <= sec[gid + 1]) {
            // fast path: full tile in one segment; 4 edges per dwordx4 load pair
            const bool q0 = (lane & 16) != 0;
            const bool q1 = (lane & 32) != 0;
            const int  c  = lane & 15;
            float accE = 0.f, accW = 0.f;         // accW counts each edge 16x
            #pragma unroll 1
            for (int i = 0; i < 64; i += 32) {
                uint4 a[8], b[8];
                #pragma unroll
                for (int u = 0; u < 8; ++u) {
                    int e = i + u * 4;
                    int s0 = sp[e], s1 = sp[e + 1], s2 = sp[e + 2], s3 = sp[e + 3];
                    int r0 = rp[e], r1 = rp[e + 1], r2 = rp[e + 2], r3 = rp[e + 3];
                    int sA = q0 ? s1 : s0;
                    int sB = q0 ? s3 : s2;
                    int s  = q1 ? sB : sA;
                    int rA = q0 ? r1 : r0;
                    int rB = q0 ? r3 : r2;
                    int r  = q1 ? rB : rA;
                    a[u] = h16[(unsigned)((s << 4) | c)];   // 4 rows / instr
                    b[u] = h16[(unsigned)((r << 4) | c)];
                }
                #pragma unroll
                for (int u = 0; u < 8; ++u) {
                    int e = i + u * 4;
                    float w0 = wp[e], w1 = wp[e + 1], w2 = wp[e + 2], w3 = wp[e + 3];
                    float wA = q0 ? w1 : w0;
                    float wB = q0 ? w3 : w2;
                    float w  = q1 ? wB : wA;
                    v2h d0 = bch(a[u].x) - bch(b[u].x);
                    v2h d1 = bch(a[u].y) - bch(b[u].y);
                    v2h d2 = bch(a[u].z) - bch(b[u].z);
                    v2h d3 = bch(a[u].w) - bch(b[u].w);
                    float tt = __builtin_amdgcn_fdot2(d0, d0, 0.f, false);
                    tt = __builtin_amdgcn_fdot2(d1, d1, tt, false);
                    tt = __builtin_amdgcn_fdot2(d2, d2, tt, false);
                    tt = __builtin_amdgcn_fdot2(d3, d3, tt, false);
                    accE = fmaf(w, tt, accE);
                    accW += w;
                }
            }
            float rE = accE, rW = accW;
            #pragma unroll
            for (int m = 32; m > 0; m >>= 1) {
                rE += __shfl_xor(rE, m);
                rW += __shfl_xor(rW, m);
            }
            if (lane == 0) {
                atomicAdd(&sga[gid], rE);
                atomicAdd(&sew[gid], rW * 0.0625f);   // / 16 lanes per edge
            }
        } else {
            // slow path: per-edge with segment flushes (uniform loads)
            float accE = 0.f, accW = 0.f;
            for (int i = 0; i < nt; ++i) {
                int e = tbu + i;
                while (e >= sec[gid + 1]) {
                    float rE = accE;
                    #pragma unroll
                    for (int m = 32; m > 0; m >>= 1) rE += __shfl_xor(rE, m);
                    if (lane == 0 && (rE != 0.f || accW != 0.f)) {
                        atomicAdd(&sga[gid], rE);
                        atomicAdd(&sew[gid], accW);
                    }
                    accE = 0.f; accW = 0.f;
                    ++gid;
                }
                int   s = sp[i];
                int   r = rp[i];
                float w = wp[i];
                unsigned a = h32[(unsigned)((s << 6) | lane)];
                unsigned b = h32[(unsigned)((r << 6) | lane)];
                v2h d = bch(a) - bch(b);
                float tt = __builtin_amdgcn_fdot2(d, d, 0.f, false);
                accE = fmaf(w, tt, accE);
                accW += w;
            }
            float rE = accE;
            #pragma unroll
            for (int m = 32; m > 0; m >>= 1) rE += __shfl_xor(rE, m);
            if (lane == 0 && (rE != 0.f || accW != 0.f)) {
                atomicAdd(&sga[gid], rE);
                atomicAdd(&sew[gid], accW);
            }
        }
    }

    __syncthreads();
    for (int g = t; g < G; g += 512) {
        float vg = sga[g], vw = sew[g];
        if (vg != 0.f || vw != 0.f) {
            atomicAdd(&ga[g], vg);      // agent relaxed RMW, IF$-served
            atomicAdd(&ew[g], vw);
        }
    }

    // ====== last-block gate: relaxed RMW (ga/ew RMWs already at IF$) ======
    __syncthreads();                 // drains this block's ga/ew atomics (vmcnt)
    if (t == 0) {
        int old = atomicAdd(&bar[1], 1);
        sec[0] = (old == NGRID - 1) ? 1 : 0;
    }
    asm volatile("" ::: "memory");
    __syncthreads();
    if (sec[0]) {
        // node_out gather: out[g][c] = (float)hh[nid[g]][c]
        for (int i = t; i < G * D_F; i += 512) {
            int g = i >> 7, c = i & (D_F - 1);
            out[i] = (float)hh[(size_t)nid[g] * D_F + c];
        }
        // loss = mean_g (ew!=0 ? ga/ew : 0); coherent reads via relaxed atomic loads
        float p = 0.f;
        for (int g = t; g < G; g += 512) {
            float w = __hip_atomic_load(&ew[g], __ATOMIC_RELAXED, __HIP_MEMORY_SCOPE_AGENT);
            float v = __hip_atomic_load(&ga[g], __ATOMIC_RELAXED, __HIP_MEMORY_SCOPE_AGENT);
            p += (w != 0.f) ? v / w : 0.f;
        }
        #pragma unroll
        for (int m = 32; m > 0; m >>= 1) p += __shfl_xor(p, m);
        if (lane == 0) sga[wave] = p;
        __syncthreads();
        if (t == 0) {
            float s = 0.f;
            #pragma unroll
            for (int w = 0; w < 8; ++w) s += sga[w];
            out[(size_t)G * D_F] = s / (float)G;
        }
    }
}

// ---------------------------------------------------------------------------
extern "C" void kernel_launch(void* const* d_in, const int* in_sizes, int n_in,
                              void* d_out, int out_size, void* d_ws, size_t ws_size,
                              hipStream_t stream) {
    const float* nodes     = (const float*)d_in[0];
    const float* edges     = (const float*)d_in[1];
    const int*   senders   = (const int*)d_in[2];
    const int*   receivers = (const int*)d_in[3];
    const int*   n_node    = (const int*)d_in[4];
    const int*   n_edge    = (const int*)d_in[5];
    const float* W1        = (const float*)d_in[6];
    const float* b1        = (const float*)d_in[7];
    const float* W2        = (const float*)d_in[8];
    const float* b2        = (const float*)d_in[9];

    const int N = in_sizes[0] / D_F;
    const int E = in_sizes[1];
    const int G = in_sizes[4];

    float* out = (float*)d_out;

    // workspace: hh f16 | W1T bf16 | W2T bf16 | ec | nid | ew | ga | bar
    _Float16*       hh  = (_Float16*)d_ws;
    unsigned short* W1T = (unsigned short*)(hh + (size_t)N * D_F);
    unsigned short* W2T = W1T + (size_t)D_F * D_H;
    int*            ec  = (int*)(W2T + (size_t)D_F * D_H);
    int*            nid = ec + (G + 1);
    float*          ew  = (float*)(nid + G);
    float*          ga  = ew + G;
    int*            bar = (int*)(ga + G);

    prep_kernel<<<(D_F * D_H + 255) / 256, 256, 0, stream>>>(
        W1, W2, n_node, n_edge, W1T, W2T, ec, nid, ew, ga, bar, G, E);

    const int nblk   = (N + 31) / 32;          // 32-row MLP tiles
    const int ntiles = (E + 63) / 64;          // 64-edge tiles

    mega_kernel<<<NGRID, 512, 0, stream>>>(
        nodes, W1T, b1, W2T, b2, hh, edges, senders, receivers,
        ec, nid, ew, ga, bar, out, N, E, G, nblk, ntiles);
}

// Round 5
// 136.032 us; speedup vs baseline: 2.7644x; 1.1365x over previous
//
#include <hip/hip_runtime.h>

#define D_F 128
#define D_H 512
#define SHS 520   // sH row stride (bf16 elems): 1040 B, 16B-aligned

typedef short v8s __attribute__((ext_vector_type(8)));
typedef float v4f __attribute__((ext_vector_type(4)));
typedef _Float16 v2h __attribute__((ext_vector_type(2)));

__device__ inline unsigned short f2bf(float f) {
    unsigned u = __float_as_uint(f);
    unsigned r = (u + 0x7fffu + ((u >> 16) & 1u)) >> 16;   // RNE
    return (unsigned short)r;
}
__device__ inline v2h bch(unsigned x) { return __builtin_bit_cast(v2h, x); }

// ---------------------------------------------------------------------------
// prep: weight conversion (all blocks) + init cumsums/zeros/counters (block 0)
// ---------------------------------------------------------------------------
__global__ __launch_bounds__(256) void prep_kernel(
    const float* __restrict__ W1, const float* __restrict__ W2,
    const int* __restrict__ n_node, const int* __restrict__ n_edge,
    unsigned short* __restrict__ W1T, unsigned short* __restrict__ W2T,
    int* __restrict__ ec, int* __restrict__ nid,
    float* __restrict__ ew, float* __restrict__ ga,
    int* __restrict__ bar, int G, int E)
{
    if (blockIdx.x == 0) {
        __shared__ int sne[512];
        __shared__ int snn[512];
        const int t = threadIdx.x;
        if (t < 2) bar[t] = 0;                    // done-gate counter
        for (int g = t; g < G; g += 256) { sne[g] = n_edge[g]; snn[g] = n_node[g]; }
        __syncthreads();
        for (int g = t; g < G; g += 256) {
            int se = 0, sn = 0;
            for (int k = 0; k < g; ++k)  se += sne[k];
            for (int k = 0; k <= g; ++k) sn += snn[k];
            ec[g]  = se;
            nid[g] = sn - 1;
            ew[g] = 0.f;
            ga[g] = 0.f;
            if (g == G - 1) {
                int tot = se + sne[g];
                ec[G] = tot > E ? tot : E;
            }
        }
    }
    int i = blockIdx.x * 256 + threadIdx.x;
    if (i < D_F * D_H) {
        int n = i >> 7, k = i & (D_F - 1);        // W1T[n][k] = W1[k][n]
        W1T[i] = f2bf(W1[k * D_H + n]);
        int n2 = i >> 9, k2 = i & (D_H - 1);      // W2T[n2][k2] = W2[k2][n2]
        W2T[i] = f2bf(W2[k2 * D_F + n2]);
    }
}

// ---------------------------------------------------------------------------
// Fused MLP via MFMA (bf16 weights, fp16 output h): 32 rows / block, 8 waves
// splitting the n-dimension. Two 16-row groups share every B (weight)
// fragment. Proven round-1 body (129.5 us total). Normal write-back stores;
// the kernel-end boundary (one wbl2+inv) publishes hh to the edge kernel.
// ---------------------------------------------------------------------------
__global__ __launch_bounds__(512) void mlp_mfma_kernel(
    const float* __restrict__ nodes,
    const unsigned short* __restrict__ W1T, const float* __restrict__ b1,
    const unsigned short* __restrict__ W2T, const float* __restrict__ b2,
    _Float16* __restrict__ hh, int N)
{
    __shared__ unsigned short sH[32 * SHS];   // 33.3 KB

    const int t    = threadIdx.x;
    const int wave = t >> 6;        // 0..7
    const int lane = t & 63;
    const int li   = lane & 15;
    const int quad = lane >> 4;
    const int row0 = blockIdx.x * 32;

    // A fragments: two 16-row groups (same for all 8 waves; L1-served)
    v8s a1[2][4];
    #pragma unroll
    for (int rg = 0; rg < 2; ++rg) {
        int r = min(row0 + rg * 16 + li, N - 1);
        const float* xp = nodes + (size_t)r * D_F + quad * 8;
        #pragma unroll
        for (int ks = 0; ks < 4; ++ks) {
            float4 f0 = *(const float4*)(xp + ks * 32);
            float4 f1 = *(const float4*)(xp + ks * 32 + 4);
            v8s v;
            v[0] = (short)f2bf(f0.x); v[1] = (short)f2bf(f0.y);
            v[2] = (short)f2bf(f0.z); v[3] = (short)f2bf(f0.w);
            v[4] = (short)f2bf(f1.x); v[5] = (short)f2bf(f1.y);
            v[6] = (short)f2bf(f1.z); v[7] = (short)f2bf(f1.w);
            a1[rg][ks] = v;
        }
    }

    // GEMM1: wave covers hidden cols [wave*64, wave*64+64)
    #pragma unroll 2
    for (int jj = 0; jj < 4; ++jj) {
        const int n0 = (wave * 4 + jj) * 16;
        const unsigned short* wp = W1T + (size_t)(n0 + li) * D_F + quad * 8;
        v4f acc0 = {0.f, 0.f, 0.f, 0.f};
        v4f acc1 = {0.f, 0.f, 0.f, 0.f};
        #pragma unroll
        for (int ks = 0; ks < 4; ++ks) {
            v8s b = *(const v8s*)(wp + ks * 32);
            acc0 = __builtin_amdgcn_mfma_f32_16x16x32_bf16(a1[0][ks], b, acc0, 0, 0, 0);
            acc1 = __builtin_amdgcn_mfma_f32_16x16x32_bf16(a1[1][ks], b, acc1, 0, 0, 0);
        }
        float bias = b1[n0 + li];
        #pragma unroll
        for (int r = 0; r < 4; ++r) {
            int m = quad * 4 + r;                 // C layout: row = quad*4+reg
            sH[m * SHS + n0 + li]        = f2bf(fmaxf(acc0[r] + bias, 0.f));
            sH[(16 + m) * SHS + n0 + li] = f2bf(fmaxf(acc1[r] + bias, 0.f));
        }
    }
    __syncthreads();

    // GEMM2: wave covers output cols [wave*16, wave*16+16); chunk-4 buffers
    {
        const int n0 = wave * 16;
        const unsigned short* wp = W2T + (size_t)(n0 + li) * D_H + quad * 8;
        v4f acc0 = {0.f, 0.f, 0.f, 0.f};
        v4f acc1 = {0.f, 0.f, 0.f, 0.f};
        #pragma unroll
        for (int kc = 0; kc < 4; ++kc) {
            v8s bb[4], aH0[4], aH1[4];
            #pragma unroll
            for (int u = 0; u < 4; ++u) {
                int ks = kc * 4 + u;
                bb[u]  = *(const v8s*)(wp + ks * 32);
                aH0[u] = *(const v8s*)(sH + li * SHS + ks * 32 + quad * 8);
                aH1[u] = *(const v8s*)(sH + (16 + li) * SHS + ks * 32 + quad * 8);
            }
            #pragma unroll
            for (int u = 0; u < 4; ++u) {
                acc0 = __builtin_amdgcn_mfma_f32_16x16x32_bf16(aH0[u], bb[u], acc0, 0, 0, 0);
                acc1 = __builtin_amdgcn_mfma_f32_16x16x32_bf16(aH1[u], bb[u], acc1, 0, 0, 0);
            }
        }
        float bias = b2[n0 + li];
        #pragma unroll
        for (int r = 0; r < 4; ++r) {
            int g0 = row0 + quad * 4 + r;
            if (g0 < N) hh[(size_t)g0 * D_F + n0 + li] = (_Float16)(acc0[r] + bias);
            int g1 = row0 + 16 + quad * 4 + r;
            if (g1 < N) hh[(size_t)g1 * D_F + n0 + li] = (_Float16)(acc1[r] + bias);
        }
    }
}

// ---------------------------------------------------------------------------
// Edge stage + fused finalize: 512-thread blocks, 8 waves, one exact 64-edge
// tile per wave. dwordx4 gathers (4 edges per load pair). LDS-staged segment
// atomics -> global relaxed RMW (IF$-served). Last block through the relaxed
// done-gate performs node_out gather + loss (round-4-proven pattern), saving
// the separate finalize dispatch + boundary.
// ---------------------------------------------------------------------------
__global__ __launch_bounds__(512) void edge_kernel(
    const _Float16* __restrict__ hh, const float* __restrict__ wedge,
    const int* __restrict__ senders, const int* __restrict__ receivers,
    const int* __restrict__ ec, const int* __restrict__ nid,
    float* __restrict__ ew, float* __restrict__ ga,
    int* __restrict__ bar, float* __restrict__ out,
    int E, int G)
{
    __shared__ int   sec[513];
    __shared__ float sga[512];
    __shared__ float sew[512];
    const int t = threadIdx.x;
    for (int i = t; i <= G; i += 512) sec[i] = ec[i];
    for (int i = t; i < G;  i += 512) { sga[i] = 0.f; sew[i] = 0.f; }
    __syncthreads();

    const unsigned* __restrict__ h32 = (const unsigned*)hh;   // row = 64 dwords
    const uint4*    __restrict__ h16 = (const uint4*)hh;      // row = 16 uint4
    const int lane = t & 63;
    const int wave = t >> 6;
    const int tb   = (blockIdx.x * 8 + wave) << 6;

    if (tb < E) {
        const int tbu = __builtin_amdgcn_readfirstlane(tb);   // uniform tile base
        const int nt  = min(64, E - tbu);

        int gid;
        { int lo = 0, hi = G - 1;
          while (lo < hi) { int m = (lo + hi + 1) >> 1; if (sec[m] <= tbu) lo = m; else hi = m - 1; }
          gid = lo; }

        // uniform pointers -> scalar loads
        const int*   __restrict__ sp = senders   + tbu;
        const int*   __restrict__ rp = receivers + tbu;
        const float* __restrict__ wp = wedge     + tbu;

        if (nt == 64 && tbu + 64 <= sec[gid + 1]) {
            // ---- fast path: full tile in one segment; 4 edges / load pair ----
            const bool q0 = (lane & 16) != 0;
            const bool q1 = (lane & 32) != 0;
            const int  c  = lane & 15;          // uint4 column within row
            float accE = 0.f, accW = 0.f;       // accW counts each edge 16x
            #pragma unroll 1
            for (int i = 0; i < 64; i += 32) {
                uint4 a[8], b[8];
                #pragma unroll
                for (int u = 0; u < 8; ++u) {
                    int e = i + u * 4;
                    int s0 = sp[e], s1 = sp[e + 1], s2 = sp[e + 2], s3 = sp[e + 3];
                    int r0 = rp[e], r1 = rp[e + 1], r2 = rp[e + 2], r3 = rp[e + 3];
                    int sA = q0 ? s1 : s0;
                    int sB = q0 ? s3 : s2;
                    int s  = q1 ? sB : sA;
                    int rA = q0 ? r1 : r0;
                    int rB = q0 ? r3 : r2;
                    int r  = q1 ? rB : rA;
                    a[u] = h16[(unsigned)((s << 4) | c)];   // 4 rows / instr
                    b[u] = h16[(unsigned)((r << 4) | c)];
                }
                #pragma unroll
                for (int u = 0; u < 8; ++u) {
                    int e = i + u * 4;
                    float w0 = wp[e], w1 = wp[e + 1], w2 = wp[e + 2], w3 = wp[e + 3];
                    float wA = q0 ? w1 : w0;
                    float wB = q0 ? w3 : w2;
                    float w  = q1 ? wB : wA;
                    v2h d0 = bch(a[u].x) - bch(b[u].x);
                    v2h d1 = bch(a[u].y) - bch(b[u].y);
                    v2h d2 = bch(a[u].z) - bch(b[u].z);
                    v2h d3 = bch(a[u].w) - bch(b[u].w);
                    float tt = __builtin_amdgcn_fdot2(d0, d0, 0.f, false);
                    tt = __builtin_amdgcn_fdot2(d1, d1, tt, false);
                    tt = __builtin_amdgcn_fdot2(d2, d2, tt, false);
                    tt = __builtin_amdgcn_fdot2(d3, d3, tt, false);
                    accE = fmaf(w, tt, accE);
                    accW += w;
                }
            }
            float rE = accE, rW = accW;
            #pragma unroll
            for (int m = 32; m > 0; m >>= 1) {
                rE += __shfl_xor(rE, m);
                rW += __shfl_xor(rW, m);
            }
            if (lane == 0) {
                atomicAdd(&sga[gid], rE);
                atomicAdd(&sew[gid], rW * 0.0625f);   // / 16 lanes per edge
            }
        } else {
            // ---- slow path: per-edge with segment flushes (uniform loads) ----
            float accE = 0.f, accW = 0.f;
            for (int i = 0; i < nt; ++i) {
                int e = tbu + i;
                while (e >= sec[gid + 1]) {
                    float rE = accE;
                    #pragma unroll
                    for (int m = 32; m > 0; m >>= 1) rE += __shfl_xor(rE, m);
                    if (lane == 0 && (rE != 0.f || accW != 0.f)) {
                        atomicAdd(&sga[gid], rE);
                        atomicAdd(&sew[gid], accW);
                    }
                    accE = 0.f; accW = 0.f;
                    ++gid;
                }
                int   s = sp[i];
                int   r = rp[i];
                float w = wp[i];
                unsigned a = h32[(unsigned)((s << 6) | lane)];
                unsigned b = h32[(unsigned)((r << 6) | lane)];
                v2h d = bch(a) - bch(b);
                float tt = __builtin_amdgcn_fdot2(d, d, 0.f, false);
                accE = fmaf(w, tt, accE);
                accW += w;
            }
            float rE = accE;
            #pragma unroll
            for (int m = 32; m > 0; m >>= 1) rE += __shfl_xor(rE, m);
            if (lane == 0 && (rE != 0.f || accW != 0.f)) {
                atomicAdd(&sga[gid], rE);
                atomicAdd(&sew[gid], accW);
            }
        }
    }

    __syncthreads();
    for (int g = t; g < G; g += 512) {
        float vg = sga[g], vw = sew[g];
        if (vg != 0.f || vw != 0.f) {
            atomicAdd(&ga[g], vg);      // relaxed agent RMW, IF$-served
            atomicAdd(&ew[g], vw);
        }
    }

    // ====== last-block done-gate (relaxed RMW; proven in rounds 3-4) ======
    __syncthreads();                 // drains this block's ga/ew atomics (vmcnt)
    if (t == 0) {
        int old = atomicAdd(&bar[1], 1);
        sec[0] = (old == (int)gridDim.x - 1) ? 1 : 0;
    }
    asm volatile("" ::: "memory");
    __syncthreads();
    if (sec[0]) {
        // node_out gather: out[g][c] = (float)hh[nid[g]][c] (hh from prior dispatch)
        for (int i = t; i < G * D_F; i += 512) {
            int g = i >> 7, c = i & (D_F - 1);
            out[i] = (float)hh[(size_t)nid[g] * D_F + c];
        }
        // loss = mean_g (ew!=0 ? ga/ew : 0); coherent reads via relaxed atomic loads
        float p = 0.f;
        for (int g = t; g < G; g += 512) {
            float w = __hip_atomic_load(&ew[g], __ATOMIC_RELAXED, __HIP_MEMORY_SCOPE_AGENT);
            float v = __hip_atomic_load(&ga[g], __ATOMIC_RELAXED, __HIP_MEMORY_SCOPE_AGENT);
            p += (w != 0.f) ? v / w : 0.f;
        }
        #pragma unroll
        for (int m = 32; m > 0; m >>= 1) p += __shfl_xor(p, m);
        if (lane == 0) sga[wave] = p;
        __syncthreads();
        if (t == 0) {
            float s = 0.f;
            #pragma unroll
            for (int w = 0; w < 8; ++w) s += sga[w];
            out[(size_t)G * D_F] = s / (float)G;
        }
    }
}

// ---------------------------------------------------------------------------
extern "C" void kernel_launch(void* const* d_in, const int* in_sizes, int n_in,
                              void* d_out, int out_size, void* d_ws, size_t ws_size,
                              hipStream_t stream) {
    const float* nodes     = (const float*)d_in[0];
    const float* edges     = (const float*)d_in[1];
    const int*   senders   = (const int*)d_in[2];
    const int*   receivers = (const int*)d_in[3];
    const int*   n_node    = (const int*)d_in[4];
    const int*   n_edge    = (const int*)d_in[5];
    const float* W1        = (const float*)d_in[6];
    const float* b1        = (const float*)d_in[7];
    const float* W2        = (const float*)d_in[8];
    const float* b2        = (const float*)d_in[9];

    const int N = in_sizes[0] / D_F;
    const int E = in_sizes[1];
    const int G = in_sizes[4];

    float* out = (float*)d_out;

    // workspace: hh f16 | W1T bf16 | W2T bf16 | ec | nid | ew | ga | bar
    _Float16*       hh  = (_Float16*)d_ws;
    unsigned short* W1T = (unsigned short*)(hh + (size_t)N * D_F);
    unsigned short* W2T = W1T + (size_t)D_F * D_H;
    int*            ec  = (int*)(W2T + (size_t)D_F * D_H);
    int*            nid = ec + (G + 1);
    float*          ew  = (float*)(nid + G);
    float*          ga  = ew + G;
    int*            bar = (int*)(ga + G);

    prep_kernel<<<(D_F * D_H + 255) / 256, 256, 0, stream>>>(
        W1, W2, n_node, n_edge, W1T, W2T, ec, nid, ew, ga, bar, G, E);

    const int nblk = (N + 31) / 32;
    mlp_mfma_kernel<<<nblk, 512, 0, stream>>>(nodes, W1T, b1, W2T, b2, hh, N);

    const int ntiles = (E + 63) / 64;          // one exact 64-tile per wave
    const int nblkE  = (ntiles + 7) / 8;       // 8 waves per 512-thread block
    edge_kernel<<<nblkE, 512, 0, stream>>>(hh, edges, senders, receivers, ec,
                                           nid, ew, ga, bar, out, E, G);
}

// Round 6
// 127.776 us; speedup vs baseline: 2.9430x; 1.0646x over previous
//
#include <hip/hip_runtime.h>

#define D_F 128
#define D_H 512
#define SHS 520   // sH row stride (bf16 elems): 1040 B, 16B-aligned

typedef short v8s __attribute__((ext_vector_type(8)));
typedef float v4f __attribute__((ext_vector_type(4)));
typedef _Float16 v2h __attribute__((ext_vector_type(2)));

__device__ inline unsigned short f2bf(float f) {
    unsigned u = __float_as_uint(f);
    unsigned r = (u + 0x7fffu + ((u >> 16) & 1u)) >> 16;   // RNE
    return (unsigned short)r;
}
__device__ inline v2h bch(unsigned x) { return __builtin_bit_cast(v2h, x); }

// ---------------------------------------------------------------------------
// prep: weight conversion (all blocks) + init cumsums/zeros (block 0)
// ---------------------------------------------------------------------------
__global__ __launch_bounds__(256) void prep_kernel(
    const float* __restrict__ W1, const float* __restrict__ W2,
    const int* __restrict__ n_node, const int* __restrict__ n_edge,
    unsigned short* __restrict__ W1T, unsigned short* __restrict__ W2T,
    int* __restrict__ ec, int* __restrict__ nid,
    float* __restrict__ ew, float* __restrict__ ga, int G, int E)
{
    if (blockIdx.x == 0) {
        __shared__ int sne[512];
        __shared__ int snn[512];
        const int t = threadIdx.x;
        for (int g = t; g < G; g += 256) { sne[g] = n_edge[g]; snn[g] = n_node[g]; }
        __syncthreads();
        for (int g = t; g < G; g += 256) {
            int se = 0, sn = 0;
            for (int k = 0; k < g; ++k)  se += sne[k];
            for (int k = 0; k <= g; ++k) sn += snn[k];
            ec[g]  = se;
            nid[g] = sn - 1;
            ew[g] = 0.f;
            ga[g] = 0.f;
            if (g == G - 1) {
                int tot = se + sne[g];
                ec[G] = tot > E ? tot : E;
            }
        }
    }
    int i = blockIdx.x * 256 + threadIdx.x;
    if (i < D_F * D_H) {
        int n = i >> 7, k = i & (D_F - 1);        // W1T[n][k] = W1[k][n]
        W1T[i] = f2bf(W1[k * D_H + n]);
        int n2 = i >> 9, k2 = i & (D_H - 1);      // W2T[n2][k2] = W2[k2][n2]
        W2T[i] = f2bf(W2[k2 * D_F + n2]);
    }
}

// ---------------------------------------------------------------------------
// Fused MLP via MFMA (bf16 weights, fp16 output h): 32 rows / block, 8 waves
// splitting the n-dimension. Two 16-row groups share every B (weight)
// fragment -> 2 MFMA per B-load, half the blocks (313), half the L2 weight
// traffic vs the 16-row version.
// ---------------------------------------------------------------------------
__global__ __launch_bounds__(512) void mlp_mfma_kernel(
    const float* __restrict__ nodes,
    const unsigned short* __restrict__ W1T, const float* __restrict__ b1,
    const unsigned short* __restrict__ W2T, const float* __restrict__ b2,
    _Float16* __restrict__ hh, int N)
{
    __shared__ unsigned short sH[32 * SHS];   // 33.3 KB

    const int t    = threadIdx.x;
    const int wave = t >> 6;        // 0..7
    const int lane = t & 63;
    const int li   = lane & 15;
    const int quad = lane >> 4;
    const int row0 = blockIdx.x * 32;

    // A fragments for GEMM1: two 16-row groups (same for all 8 waves; L1)
    v8s a1[2][4];
    #pragma unroll
    for (int rg = 0; rg < 2; ++rg) {
        int r = min(row0 + rg * 16 + li, N - 1);
        const float* xp = nodes + (size_t)r * D_F + quad * 8;
        #pragma unroll
        for (int ks = 0; ks < 4; ++ks) {
            float4 f0 = *(const float4*)(xp + ks * 32);
            float4 f1 = *(const float4*)(xp + ks * 32 + 4);
            v8s v;
            v[0] = (short)f2bf(f0.x); v[1] = (short)f2bf(f0.y);
            v[2] = (short)f2bf(f0.z); v[3] = (short)f2bf(f0.w);
            v[4] = (short)f2bf(f1.x); v[5] = (short)f2bf(f1.y);
            v[6] = (short)f2bf(f1.z); v[7] = (short)f2bf(f1.w);
            a1[rg][ks] = v;
        }
    }

    // GEMM1: this wave covers hidden cols [wave*64, wave*64+64)
    #pragma unroll 2
    for (int jj = 0; jj < 4; ++jj) {
        const int n0 = (wave * 4 + jj) * 16;
        const unsigned short* wp = W1T + (size_t)(n0 + li) * D_F + quad * 8;
        v4f acc0 = {0.f, 0.f, 0.f, 0.f};
        v4f acc1 = {0.f, 0.f, 0.f, 0.f};
        #pragma unroll
        for (int ks = 0; ks < 4; ++ks) {
            v8s b = *(const v8s*)(wp + ks * 32);
            acc0 = __builtin_amdgcn_mfma_f32_16x16x32_bf16(a1[0][ks], b, acc0, 0, 0, 0);
            acc1 = __builtin_amdgcn_mfma_f32_16x16x32_bf16(a1[1][ks], b, acc1, 0, 0, 0);
        }
        float bias = b1[n0 + li];
        #pragma unroll
        for (int r = 0; r < 4; ++r) {
            int m = quad * 4 + r;                 // C layout: row = quad*4+reg
            sH[m * SHS + n0 + li]        = f2bf(fmaxf(acc0[r] + bias, 0.f));
            sH[(16 + m) * SHS + n0 + li] = f2bf(fmaxf(acc1[r] + bias, 0.f));
        }
    }
    __syncthreads();

    // GEMM2: this wave covers output cols [wave*16, wave*16+16)
    {
        const int n0 = wave * 16;
        const unsigned short* wp = W2T + (size_t)(n0 + li) * D_H + quad * 8;
        v4f acc0 = {0.f, 0.f, 0.f, 0.f};
        v4f acc1 = {0.f, 0.f, 0.f, 0.f};
        #pragma unroll
        for (int kc = 0; kc < 4; ++kc) {
            v8s bb[4], aH0[4], aH1[4];
            #pragma unroll
            for (int u = 0; u < 4; ++u) {
                int ks = kc * 4 + u;
                bb[u]  = *(const v8s*)(wp + ks * 32);
                aH0[u] = *(const v8s*)(sH + li * SHS + ks * 32 + quad * 8);
                aH1[u] = *(const v8s*)(sH + (16 + li) * SHS + ks * 32 + quad * 8);
            }
            #pragma unroll
            for (int u = 0; u < 4; ++u) {
                acc0 = __builtin_amdgcn_mfma_f32_16x16x32_bf16(aH0[u], bb[u], acc0, 0, 0, 0);
                acc1 = __builtin_amdgcn_mfma_f32_16x16x32_bf16(aH1[u], bb[u], acc1, 0, 0, 0);
            }
        }
        float bias = b2[n0 + li];
        #pragma unroll
        for (int r = 0; r < 4; ++r) {
            int g0 = row0 + quad * 4 + r;
            if (g0 < N) hh[(size_t)g0 * D_F + n0 + li] = (_Float16)(acc0[r] + bias);
            int g1 = row0 + 16 + quad * 4 + r;
            if (g1 < N) hh[(size_t)g1 * D_F + n0 + li] = (_Float16)(acc1[r] + bias);
        }
    }
}

// ---------------------------------------------------------------------------
// Edge stage: 512-thread blocks, 8 waves, ONE exact 64-edge tile per wave.
// Fast path: dwordx4 gathers, 4 edges per load pair -- each quad of 16 lanes
// carries one edge's full 256 B row (16 B/lane, 1 KB/instruction). Gather
// instruction count is 4x lower than the dword version; bytes identical.
// Scalar-loaded (constant-cache) indices/weights selected per-quad via
// cndmask. LDS-staged atomics; no device fence.
// ---------------------------------------------------------------------------
__global__ __launch_bounds__(512) void edge_kernel(
    const _Float16* __restrict__ hh, const float* __restrict__ wedge,
    const int* __restrict__ senders, const int* __restrict__ receivers,
    const int* __restrict__ ec,
    float* __restrict__ ew, float* __restrict__ ga,
    int E, int G)
{
    __shared__ int   sec[513];
    __shared__ float sga[512];
    __shared__ float sew[512];
    const int t = threadIdx.x;
    for (int i = t; i <= G; i += 512) sec[i] = ec[i];
    for (int i = t; i < G;  i += 512) { sga[i] = 0.f; sew[i] = 0.f; }
    __syncthreads();

    const unsigned* __restrict__ h32 = (const unsigned*)hh;   // row = 64 dwords
    const uint4*    __restrict__ h16 = (const uint4*)hh;      // row = 16 uint4
    const int lane = t & 63;
    const int tb   = (blockIdx.x * 8 + (t >> 6)) << 6;

    if (tb < E) {
        const int tbu = __builtin_amdgcn_readfirstlane(tb);   // uniform tile base
        const int nt  = min(64, E - tbu);

        int gid;
        { int lo = 0, hi = G - 1;
          while (lo < hi) { int m = (lo + hi + 1) >> 1; if (sec[m] <= tbu) lo = m; else hi = m - 1; }
          gid = lo; }

        // uniform pointers -> scalar loads
        const int*   __restrict__ sp = senders   + tbu;
        const int*   __restrict__ rp = receivers + tbu;
        const float* __restrict__ wp = wedge     + tbu;

        if (nt == 64 && tbu + 64 <= sec[gid + 1]) {
            // ---- fast path: full tile in one segment; 4 edges / load pair ----
            const bool q0 = (lane & 16) != 0;
            const bool q1 = (lane & 32) != 0;
            const int  c  = lane & 15;          // uint4 column within row
            float accE = 0.f, accW = 0.f;       // accW counts each edge 16x
            #pragma unroll 1
            for (int i = 0; i < 64; i += 32) {
                uint4 a[8], b[8];
                #pragma unroll
                for (int u = 0; u < 8; ++u) {
                    int e = i + u * 4;
                    int s0 = sp[e], s1 = sp[e + 1], s2 = sp[e + 2], s3 = sp[e + 3];
                    int r0 = rp[e], r1 = rp[e + 1], r2 = rp[e + 2], r3 = rp[e + 3];
                    int sA = q0 ? s1 : s0;
                    int sB = q0 ? s3 : s2;
                    int s  = q1 ? sB : sA;
                    int rA = q0 ? r1 : r0;
                    int rB = q0 ? r3 : r2;
                    int r  = q1 ? rB : rA;
                    a[u] = h16[(unsigned)((s << 4) | c)];   // 4 rows / instr
                    b[u] = h16[(unsigned)((r << 4) | c)];
                }
                #pragma unroll
                for (int u = 0; u < 8; ++u) {
                    int e = i + u * 4;
                    float w0 = wp[e], w1 = wp[e + 1], w2 = wp[e + 2], w3 = wp[e + 3];
                    float wA = q0 ? w1 : w0;
                    float wB = q0 ? w3 : w2;
                    float w  = q1 ? wB : wA;
                    v2h d0 = bch(a[u].x) - bch(b[u].x);
                    v2h d1 = bch(a[u].y) - bch(b[u].y);
                    v2h d2 = bch(a[u].z) - bch(b[u].z);
                    v2h d3 = bch(a[u].w) - bch(b[u].w);
                    float tt = __builtin_amdgcn_fdot2(d0, d0, 0.f, false);
                    tt = __builtin_amdgcn_fdot2(d1, d1, tt, false);
                    tt = __builtin_amdgcn_fdot2(d2, d2, tt, false);
                    tt = __builtin_amdgcn_fdot2(d3, d3, tt, false);
                    accE = fmaf(w, tt, accE);
                    accW += w;
                }
            }
            float rE = accE, rW = accW;
            #pragma unroll
            for (int m = 32; m > 0; m >>= 1) {
                rE += __shfl_xor(rE, m);
                rW += __shfl_xor(rW, m);
            }
            if (lane == 0) {
                atomicAdd(&sga[gid], rE);
                atomicAdd(&sew[gid], rW * 0.0625f);   // / 16 lanes per edge
            }
        } else {
            // ---- slow path: per-edge with segment flushes (uniform loads) ----
            float accE = 0.f, accW = 0.f;
            for (int i = 0; i < nt; ++i) {
                int e = tbu + i;
                while (e >= sec[gid + 1]) {
                    float rE = accE;
                    #pragma unroll
                    for (int m = 32; m > 0; m >>= 1) rE += __shfl_xor(rE, m);
                    if (lane == 0 && (rE != 0.f || accW != 0.f)) {
                        atomicAdd(&sga[gid], rE);
                        atomicAdd(&sew[gid], accW);
                    }
                    accE = 0.f; accW = 0.f;
                    ++gid;
                }
                int   s = sp[i];
                int   r = rp[i];
                float w = wp[i];
                unsigned a = h32[(unsigned)((s << 6) | lane)];
                unsigned b = h32[(unsigned)((r << 6) | lane)];
                v2h d = bch(a) - bch(b);
                float tt = __builtin_amdgcn_fdot2(d, d, 0.f, false);
                accE = fmaf(w, tt, accE);
                accW += w;
            }
            float rE = accE;
            #pragma unroll
            for (int m = 32; m > 0; m >>= 1) rE += __shfl_xor(rE, m);
            if (lane == 0 && (rE != 0.f || accW != 0.f)) {
                atomicAdd(&sga[gid], rE);
                atomicAdd(&sew[gid], accW);
            }
        }
    }

    __syncthreads();
    for (int g = t; g < G; g += 512) {
        float vg = sga[g], vw = sew[g];
        if (vg != 0.f || vw != 0.f) {
            atomicAdd(&ga[g], vg);
            atomicAdd(&ew[g], vw);
        }
    }
}

// ---------------------------------------------------------------------------
// Finalize: block g < G gathers node_out row; block G computes loss.
// ---------------------------------------------------------------------------
__global__ __launch_bounds__(128) void finalize_kernel(
    const _Float16* __restrict__ hh, const int* __restrict__ nid,
    const float* __restrict__ ew, const float* __restrict__ ga,
    float* __restrict__ out, int G)
{
    const int g = blockIdx.x;
    const int t = threadIdx.x;
    if (g < G) {
        int src = nid[g];
        out[(size_t)g * D_F + t] = (float)hh[(size_t)src * D_F + t];
    } else {
        float p = 0.f;
        for (int i = t; i < G; i += 128) {
            float w = ew[i];
            p += (w != 0.f) ? ga[i] / w : 0.f;
        }
        #pragma unroll
        for (int m = 32; m > 0; m >>= 1) p += __shfl_xor(p, m);
        __shared__ float sp[2];
        if ((t & 63) == 0) sp[t >> 6] = p;
        __syncthreads();
        if (t == 0) out[(size_t)G * D_F] = (sp[0] + sp[1]) / (float)G;
    }
}

// ---------------------------------------------------------------------------
extern "C" void kernel_launch(void* const* d_in, const int* in_sizes, int n_in,
                              void* d_out, int out_size, void* d_ws, size_t ws_size,
                              hipStream_t stream) {
    const float* nodes     = (const float*)d_in[0];
    const float* edges     = (const float*)d_in[1];
    const int*   senders   = (const int*)d_in[2];
    const int*   receivers = (const int*)d_in[3];
    const int*   n_node    = (const int*)d_in[4];
    const int*   n_edge    = (const int*)d_in[5];
    const float* W1        = (const float*)d_in[6];
    const float* b1        = (const float*)d_in[7];
    const float* W2        = (const float*)d_in[8];
    const float* b2        = (const float*)d_in[9];

    const int N = in_sizes[0] / D_F;
    const int E = in_sizes[1];
    const int G = in_sizes[4];

    float* out = (float*)d_out;

    // workspace: hh f16 | W1T bf16 | W2T bf16 | ec | nid | ew | ga
    _Float16*       hh  = (_Float16*)d_ws;
    unsigned short* W1T = (unsigned short*)(hh + (size_t)N * D_F);
    unsigned short* W2T = W1T + (size_t)D_F * D_H;
    int*            ec  = (int*)(W2T + (size_t)D_F * D_H);
    int*            nid = ec + (G + 1);
    float*          ew  = (float*)(nid + G);
    float*          ga  = ew + G;

    prep_kernel<<<(D_F * D_H + 255) / 256, 256, 0, stream>>>(
        W1, W2, n_node, n_edge, W1T, W2T, ec, nid, ew, ga, G, E);

    const int nblk = (N + 31) / 32;
    mlp_mfma_kernel<<<nblk, 512, 0, stream>>>(nodes, W1T, b1, W2T, b2, hh, N);

    const int ntiles = (E + 63) / 64;          // one exact 64-tile per wave
    const int nblkE  = (ntiles + 7) / 8;       // 8 waves per 512-thread block
    edge_kernel<<<nblkE, 512, 0, stream>>>(hh, edges, senders, receivers, ec,
                                           ew, ga, E, G);

    finalize_kernel<<<G + 1, 128, 0, stream>>>(hh, nid, ew, ga, out, G);
}